// Round 2
// baseline (1041.634 us; speedup 1.0000x reference)
//
#include <hip/hip_runtime.h>
#include <hip/hip_bf16.h>

// 2-layer 4-direction MDLSTM over a height-1 strip.
//   B=256, Wd=2048, OUT=11, NDIR=4, gates [i, f_w, f_h(dead), o, a]
//
// One block per batch b, 256 threads = 4 waves = 4 directions.
//  - height-sum of x computed into LDS xw[2048] (8 KB) by the whole block
//  - each wave runs its direction's 2048-step recurrence
//  - direction sum accumulated in LDS fp32 acc[2048*11] (88 KB) via ds atomics
//  - block writes y1 / out with plain coalesced stores (no global atomics,
//    no memsets, no d_ws overflow: y1 is the ONLY workspace user)
//
// Wave layout: lane t<44 owns gate (t%11) of class t/11 in {i, f_w, o, a};
// U/W columns skip the dead f_h block (cols 22..32). h state broadcast as
// wave-uniform scalars via v_readlane (SGPR operand of v_fma in the dot).

#define NOUT 11
#define WD 2048
#define NB 256
#define Y1N (WD * NOUT)  // 22528 elements per batch

__device__ __forceinline__ float rl(float v, int l) {
  return __int_as_float(__builtin_amdgcn_readlane(__float_as_int(v), l));
}

// y1 load/store, templated on storage type (fp32 if ws_size allows, else bf16)
__device__ __forceinline__ float ldy(const float* p) { return *p; }
__device__ __forceinline__ float ldy(const __hip_bfloat16* p) {
  return __bfloat162float(*p);
}
__device__ __forceinline__ void sty(float* p, float v) { *p = v; }
__device__ __forceinline__ void sty(__hip_bfloat16* p, float v) {
  *p = __float2bfloat16(v);
}

// One LSTM step. G_INIT sets a0..a3 with the input (Wx + b) contribution;
// STORE consumes (wa, hn) for lanes < NOUT.
#define LSTM_BODY(G_INIT, W_IDX, STORE)                                        \
  do {                                                                         \
    float g;                                                                   \
    {                                                                          \
      G_INIT                                                                   \
      a3 = fmaf(h0, Uc[0], a3);  a0 = fmaf(h1, Uc[1], a0);                     \
      a1 = fmaf(h2, Uc[2], a1);  a2 = fmaf(h3, Uc[3], a2);                     \
      a3 = fmaf(h4, Uc[4], a3);  a0 = fmaf(h5, Uc[5], a0);                     \
      a1 = fmaf(h6, Uc[6], a1);  a2 = fmaf(h7, Uc[7], a2);                     \
      a3 = fmaf(h8, Uc[8], a3);  a0 = fmaf(h9, Uc[9], a0);                     \
      a1 = fmaf(h10, Uc[10], a1);                                              \
      g = (a0 + a1) + (a2 + a3);                                               \
    }                                                                          \
    const float arg = isA ? (g + g) : g;                                       \
    const float e = __expf(-arg);                                              \
    const float sg = __builtin_amdgcn_rcpf(1.0f + e);                          \
    const float act = isA ? fmaf(2.0f, sg, -1.0f) : sg;                        \
    const float fv = __shfl(act, base + 11, 64);                               \
    const float ov = __shfl(act, base + 22, 64);                               \
    const float av = __shfl(act, base + 33, 64);                               \
    c = fmaf(fv, c, act * av);                                                 \
    const float e2 = __expf(-2.0f * c);                                        \
    const float th = fmaf(2.0f, __builtin_amdgcn_rcpf(1.0f + e2), -1.0f);      \
    const float hn = ov * th;                                                  \
    h0 = rl(hn, 0); h1 = rl(hn, 1); h2 = rl(hn, 2); h3 = rl(hn, 3);            \
    h4 = rl(hn, 4); h5 = rl(hn, 5); h6 = rl(hn, 6); h7 = rl(hn, 7);            \
    h8 = rl(hn, 8); h9 = rl(hn, 9); h10 = rl(hn, 10);                          \
    if (lane < NOUT) {                                                         \
      const int wa = fwd ? (W_IDX) : (WD - 1 - (W_IDX));                       \
      STORE                                                                    \
    }                                                                          \
  } while (0)

// --------------------------------------------------------------------------
// Layer 1: Cin = 1 (height-summed x), input staged in LDS
// --------------------------------------------------------------------------
template <typename YT>
__global__ __launch_bounds__(256) void lstm_layer1(
    const float* __restrict__ x, const float* __restrict__ W0,
    const float* __restrict__ U0, const float* __restrict__ b0,
    YT* __restrict__ y1) {
  __shared__ float xw[WD];    // 8 KB: height-summed input strip
  __shared__ float acc[Y1N];  // 88 KB: 4-direction h accumulator

  const int tid = threadIdx.x;
  const int b = blockIdx.x;

  // Phase A: height reduction x[b,0,:,w] -> xw[w], and zero acc.
  const float* xb = x + (size_t)b * 32 * WD;
  for (int w = tid; w < WD; w += 256) {
    float s = 0.f;
#pragma unroll
    for (int h = 0; h < 32; ++h) s += xb[h * WD + w];
    xw[w] = s;
  }
  for (int i = tid; i < Y1N; i += 256) acc[i] = 0.f;
  __syncthreads();

  // Phase B: recurrence, one wave per direction.
  const int lane = tid & 63;
  const int d = tid >> 6;
  const int t = (lane < 44) ? lane : 0;
  const int cls = t / 11;
  const int col = t + ((cls >= 2) ? 11 : 0);  // skip dead f_h cols 22..32
  const bool isA = (cls == 3);
  const int base = (lane < NOUT) ? lane : 0;
  const bool fwd = ((d & 1) == 0);

  const float Wc0 = W0[d * 55 + col];
  const float bc = b0[d * 55 + col];
  float Uc[11];
#pragma unroll
  for (int s = 0; s < 11; ++s) Uc[s] = U0[(d * 11 + s) * 55 + col];

  float h0 = 0, h1 = 0, h2 = 0, h3 = 0, h4 = 0, h5 = 0, h6 = 0, h7 = 0,
        h8 = 0, h9 = 0, h10 = 0, c = 0;

  auto LDX = [&](int w) -> float {
    const int wa = fwd ? w : (WD - 1 - w);
    return xw[wa];  // wave-uniform LDS read (broadcast)
  };

#define L1_INIT(XV)                     \
  float a0 = fmaf((XV), Wc0, bc);       \
  float a1 = 0.f, a2 = 0.f, a3 = 0.f;
#define ACC_STORE atomicAdd(&acc[wa * NOUT + lane], hn);

  float p0 = LDX(0), p1 = LDX(1), p2 = LDX(2), p3 = LDX(3);
  for (int w = 0; w < WD; w += 4) {
    const float q0 = p0, q1 = p1, q2 = p2, q3 = p3;
    const int wn = (w + 4 < WD) ? (w + 4) : (WD - 4);
    p0 = LDX(wn); p1 = LDX(wn + 1); p2 = LDX(wn + 2); p3 = LDX(wn + 3);
    LSTM_BODY(L1_INIT(q0), w, ACC_STORE);
    LSTM_BODY(L1_INIT(q1), w + 1, ACC_STORE);
    LSTM_BODY(L1_INIT(q2), w + 2, ACC_STORE);
    LSTM_BODY(L1_INIT(q3), w + 3, ACC_STORE);
  }

  // Phase C: write the direction-summed strip.
  __syncthreads();
  YT* yb = y1 + (size_t)b * Y1N;
  for (int i = tid; i < Y1N; i += 256) sty(yb + i, acc[i]);
}

// --------------------------------------------------------------------------
// Layer 2: Cin = 11 (y1), output transposed to [b][j][w]
// --------------------------------------------------------------------------
template <typename YT>
__global__ __launch_bounds__(256) void lstm_layer2(
    const YT* __restrict__ y1, const float* __restrict__ W1,
    const float* __restrict__ U1, const float* __restrict__ b1,
    float* __restrict__ out) {
  __shared__ float acc[Y1N];  // 88 KB

  const int tid = threadIdx.x;
  const int b = blockIdx.x;
  for (int i = tid; i < Y1N; i += 256) acc[i] = 0.f;
  __syncthreads();

  const int lane = tid & 63;
  const int d = tid >> 6;
  const int t = (lane < 44) ? lane : 0;
  const int cls = t / 11;
  const int col = t + ((cls >= 2) ? 11 : 0);
  const bool isA = (cls == 3);
  const int base = (lane < NOUT) ? lane : 0;
  const bool fwd = ((d & 1) == 0);

  const float bc = b1[d * 55 + col];
  float Wc[11], Uc[11];
#pragma unroll
  for (int s = 0; s < 11; ++s) {
    Wc[s] = W1[(d * 11 + s) * 55 + col];
    Uc[s] = U1[(d * 11 + s) * 55 + col];
  }

  const YT* yrow = y1 + (size_t)b * Y1N;
  const int li = (lane < NOUT) ? lane : (NOUT - 1);

  float h0 = 0, h1 = 0, h2 = 0, h3 = 0, h4 = 0, h5 = 0, h6 = 0, h7 = 0,
        h8 = 0, h9 = 0, h10 = 0, c = 0;

  auto LDY = [&](int w) -> float {
    const int wa = fwd ? w : (WD - 1 - w);
    return ldy(yrow + wa * NOUT + li);  // lanes 0..10 cover one record
  };

#define L2_INIT(PV)                                                            \
  const float yv0 = rl(PV, 0), yv1 = rl(PV, 1), yv2 = rl(PV, 2),               \
              yv3 = rl(PV, 3), yv4 = rl(PV, 4), yv5 = rl(PV, 5),               \
              yv6 = rl(PV, 6), yv7 = rl(PV, 7), yv8 = rl(PV, 8),               \
              yv9 = rl(PV, 9), yv10 = rl(PV, 10);                              \
  float a0 = fmaf(yv0, Wc[0], bc);                                             \
  float a1 = yv1 * Wc[1];                                                      \
  float a2 = yv2 * Wc[2];                                                      \
  float a3 = yv3 * Wc[3];                                                      \
  a0 = fmaf(yv4, Wc[4], a0); a1 = fmaf(yv5, Wc[5], a1);                        \
  a2 = fmaf(yv6, Wc[6], a2); a3 = fmaf(yv7, Wc[7], a3);                        \
  a0 = fmaf(yv8, Wc[8], a0); a1 = fmaf(yv9, Wc[9], a1);                        \
  a2 = fmaf(yv10, Wc[10], a2);

  float p0 = LDY(0), p1 = LDY(1), p2 = LDY(2), p3 = LDY(3);
  for (int w = 0; w < WD; w += 4) {
    const float q0 = p0, q1 = p1, q2 = p2, q3 = p3;
    const int wn = (w + 4 < WD) ? (w + 4) : (WD - 4);
    p0 = LDY(wn); p1 = LDY(wn + 1); p2 = LDY(wn + 2); p3 = LDY(wn + 3);
    LSTM_BODY(L2_INIT(q0), w, ACC_STORE);
    LSTM_BODY(L2_INIT(q1), w + 1, ACC_STORE);
    LSTM_BODY(L2_INIT(q2), w + 2, ACC_STORE);
    LSTM_BODY(L2_INIT(q3), w + 3, ACC_STORE);
  }

  // Transposed store: out[b][j][w] = acc[w*NOUT + j], coalesced in w.
  __syncthreads();
  float* ob = out + (size_t)b * Y1N;
  for (int i = tid; i < Y1N; i += 256) {
    const int j = i >> 11;        // i / WD
    const int w = i & (WD - 1);   // i % WD
    ob[i] = acc[w * NOUT + j];
  }
}

// --------------------------------------------------------------------------
extern "C" void kernel_launch(void* const* d_in, const int* in_sizes, int n_in,
                              void* d_out, int out_size, void* d_ws,
                              size_t ws_size, hipStream_t stream) {
  const float* x  = (const float*)d_in[0];
  const float* W0 = (const float*)d_in[1];
  const float* U0 = (const float*)d_in[2];
  const float* b0 = (const float*)d_in[3];
  const float* W1 = (const float*)d_in[4];
  const float* U1 = (const float*)d_in[5];
  const float* b1 = (const float*)d_in[6];
  float* out = (float*)d_out;

  const size_t y1_f32_bytes = (size_t)NB * Y1N * sizeof(float);  // 23.1 MB

  if (ws_size >= y1_f32_bytes) {
    float* y1 = (float*)d_ws;
    lstm_layer1<float><<<NB, 256, 0, stream>>>(x, W0, U0, b0, y1);
    lstm_layer2<float><<<NB, 256, 0, stream>>>(y1, W1, U1, b1, out);
  } else {
    // bf16 y1 (11.5 MB): abs err ~2e-3 on y1 -> ~1e-3 on out, under threshold
    __hip_bfloat16* y1 = (__hip_bfloat16*)d_ws;
    lstm_layer1<__hip_bfloat16><<<NB, 256, 0, stream>>>(x, W0, U0, b0, y1);
    lstm_layer2<__hip_bfloat16><<<NB, 256, 0, stream>>>(y1, W1, U1, b1, out);
  }
}